// Round 4
// baseline (501.700 us; speedup 1.0000x reference)
//
#include <hip/hip_runtime.h>
#include <math.h>

// ---------------- problem constants ----------------
constexpr int   NN  = 100000;    // nodes
constexpr int   EE  = 1600000;   // edges
constexpr int   HH  = 128;       // hidden / in_channels
constexpr int   GG  = 128;       // graphs
constexpr float EPSV = 1e-5f;
constexpr int   NSB = 256;                     // global sub-bins
constexpr int   SUBW = (NN + NSB - 1) / NSB;   // 391 nodes per sub-bin
constexpr int   CAP2 = 8192;                   // per-sub-bin capacity (avg 6250, +24 sigma)
constexpr int   GEMM_BLOCKS = (NN + 127) / 128;  // 782
constexpr int   WHALF = 64 * 136;                // padded ushorts per (half,hl) slab = 8704
constexpr int   WLAYER = 2 * 2 * WHALF;          // per-layer split-W ushorts (2 halves x H/L)

typedef __attribute__((ext_vector_type(8))) short  short8;
typedef __attribute__((ext_vector_type(4))) float  f32x4;
typedef __attribute__((ext_vector_type(2))) float  v2f;

__device__ __forceinline__ unsigned short f2bf(float f) {
    union { float f; unsigned u; } v; v.f = f;
    unsigned r = v.u + 0x7FFF + ((v.u >> 16) & 1);   // round-to-nearest-even
    return (unsigned short)(r >> 16);
}
__device__ __forceinline__ float bf2f(unsigned short b) {
    union { unsigned u; float f; } v; v.u = ((unsigned)b) << 16;
    return v.f;
}

// ---------------- workspace layout ----------------
constexpr size_t A256(size_t x) { return (x + 255) & ~(size_t)255; }
constexpr size_t OFF_TL  = 0;                                       // tail2[256]
constexpr size_t OFF_DNV = A256(OFF_TL  + 256 * 4);                 // N floats dinv
constexpr size_t OFF_RP  = A256(OFF_DNV + (size_t)NN * 4);          // (N+1) ints
constexpr size_t OFF_SRC = A256(OFF_RP  + (size_t)(NN + 1) * 4);    // E ints sorted src
constexpr size_t OFF_B2  = A256(OFF_SRC + (size_t)EE * 4);          // 256*CAP2 uints sub-bins
constexpr size_t OFF_ED  = A256(OFF_B2  + (size_t)NSB * CAP2 * 4);  // E uint2 (src, dinv[src])
constexpr size_t OFF_WS  = A256(OFF_ED  + (size_t)EE * 8);          // 2*WLAYER ushorts split-W (layers 1,2)
constexpr size_t OFF_HW  = A256(OFF_WS  + (size_t)2 * WLAYER * 2);  // N*H bf16 (h@W)
constexpr size_t OFF_H0  = A256(OFF_HW  + (size_t)NN * HH * 2);     // N*H bf16 (h)
constexpr size_t OFF_PL  = A256(OFF_H0  + (size_t)NN * HH * 2);     // G*H f32 pooled + G f32 cnt

// ---------------- GEMM body: C[N,128] = A[N,128] @ W[128,128], MFMA bf16, split-W ----------------
template<bool FP32A>
__device__ __forceinline__ void gemm_body(const void* __restrict__ Ap,
                                          const float* __restrict__ W,
                                          const unsigned short* __restrict__ Wsp,
                                          unsigned short* __restrict__ C,
                                          int nrows, int rb) {
    __shared__ unsigned short smem[2 * WHALF];  // WtH | WtL ; reused as Cs[128][68]
    unsigned short* WtH = smem;
    unsigned short* WtL = smem + WHALF;
    int t = threadIdx.x;
    int row0 = rb * 128;
    int wv = t >> 6, lane = t & 63, m = lane & 15, q = lane >> 4;
    long rowA = row0 + wv * 32 + m;
    long rowB = rowA + 16;

    short8 a[2][4];
#pragma unroll
    for (int kc = 0; kc < 4; ++kc) {
        int ko = kc * 32 + q * 8;
        if (FP32A) {
            const float* Af = (const float*)Ap;
            float4 f0 = {0,0,0,0}, f1 = {0,0,0,0}, g0 = {0,0,0,0}, g1 = {0,0,0,0};
            if (rowA < nrows) {
                f0 = *(const float4*)(Af + rowA * 128 + ko);
                f1 = *(const float4*)(Af + rowA * 128 + ko + 4);
            }
            if (rowB < nrows) {
                g0 = *(const float4*)(Af + rowB * 128 + ko);
                g1 = *(const float4*)(Af + rowB * 128 + ko + 4);
            }
            union { short8 s; unsigned short u[8]; } ua, ub;
            ua.u[0] = f2bf(f0.x); ua.u[1] = f2bf(f0.y); ua.u[2] = f2bf(f0.z); ua.u[3] = f2bf(f0.w);
            ua.u[4] = f2bf(f1.x); ua.u[5] = f2bf(f1.y); ua.u[6] = f2bf(f1.z); ua.u[7] = f2bf(f1.w);
            ub.u[0] = f2bf(g0.x); ub.u[1] = f2bf(g0.y); ub.u[2] = f2bf(g0.z); ub.u[3] = f2bf(g0.w);
            ub.u[4] = f2bf(g1.x); ub.u[5] = f2bf(g1.y); ub.u[6] = f2bf(g1.z); ub.u[7] = f2bf(g1.w);
            a[0][kc] = ua.s; a[1][kc] = ub.s;
        } else {
            const unsigned short* Ab = (const unsigned short*)Ap;
            short8 z = {};
            a[0][kc] = (rowA < nrows) ? *(const short8*)(Ab + rowA * 128 + ko) : z;
            a[1][kc] = (rowB < nrows) ? *(const short8*)(Ab + rowB * 128 + ko) : z;
        }
    }

    for (int half = 0; half < 2; ++half) {
        int c0 = half * 64;
        __syncthreads();
        if (FP32A) {
            for (int idx = t; idx < 64 * 128; idx += 256) {
                int k = idx >> 6, c = idx & 63;
                float w = W[k * 128 + c0 + c];
                unsigned short hb = f2bf(w);
                WtH[c * 136 + k] = hb;
                WtL[c * 136 + k] = f2bf(w - bf2f(hb));
            }
        } else {
            const uint4* srcw = (const uint4*)(Wsp + (size_t)half * 2 * WHALF);
            uint4* dstw = (uint4*)smem;
            for (int i = t; i < 2176; i += 256) dstw[i] = srcw[i];
        }
        __syncthreads();
        f32x4 acc[2][4] = {};
#pragma unroll
        for (int kc = 0; kc < 4; ++kc) {
            int ko = kc * 32 + q * 8;
#pragma unroll
            for (int ct = 0; ct < 4; ++ct) {
                short8 bh = *(const short8*)(WtH + (ct * 16 + m) * 136 + ko);
                short8 bl = *(const short8*)(WtL + (ct * 16 + m) * 136 + ko);
                acc[0][ct] = __builtin_amdgcn_mfma_f32_16x16x32_bf16(a[0][kc], bh, acc[0][ct], 0, 0, 0);
                acc[0][ct] = __builtin_amdgcn_mfma_f32_16x16x32_bf16(a[0][kc], bl, acc[0][ct], 0, 0, 0);
                acc[1][ct] = __builtin_amdgcn_mfma_f32_16x16x32_bf16(a[1][kc], bh, acc[1][ct], 0, 0, 0);
                acc[1][ct] = __builtin_amdgcn_mfma_f32_16x16x32_bf16(a[1][kc], bl, acc[1][ct], 0, 0, 0);
            }
        }
        __syncthreads();
        unsigned short* Cs = smem;  // [128][68]
#pragma unroll
        for (int rt = 0; rt < 2; ++rt)
#pragma unroll
            for (int ct = 0; ct < 4; ++ct)
#pragma unroll
                for (int r = 0; r < 4; ++r) {
                    int rl = wv * 32 + rt * 16 + q * 4 + r;
                    Cs[rl * 68 + ct * 16 + m] = f2bf(acc[rt][ct][r]);
                }
        __syncthreads();
        for (int idx = t; idx < 128 * 16; idx += 256) {
            int row = idx >> 4, ch = idx & 15;
            long grow = row0 + row;
            if (grow < nrows)
                *(ushort4*)(C + grow * 128 + c0 + ch * 4) = *(const ushort4*)(Cs + row * 68 + ch * 4);
        }
    }
}

// ---------------- direct binning: edges -> 256 global sub-bins ----------------
__device__ void binall_body(const int* __restrict__ src, const int* __restrict__ dst,
                            unsigned* __restrict__ bins2, unsigned* __restrict__ tail2,
                            int b) {
    __shared__ unsigned cnt[NSB];
    __shared__ unsigned cur[NSB];
    int t = threadIdx.x;
    cnt[t] = 0;
    __syncthreads();
    const int nvec = EE / 4;                 // 400000
    int csz = (nvec + NSB - 1) / NSB;        // 1563
    int i0 = b * csz;
    int i1 = i0 + csz; if (i1 > nvec) i1 = nvec;
    const int4* d4 = (const int4*)dst;
    const int4* s4 = (const int4*)src;
    for (int i = i0 + t; i < i1; i += 256) {
        int4 d = d4[i];
        atomicAdd(&cnt[(unsigned)d.x / SUBW], 1u);
        atomicAdd(&cnt[(unsigned)d.y / SUBW], 1u);
        atomicAdd(&cnt[(unsigned)d.z / SUBW], 1u);
        atomicAdd(&cnt[(unsigned)d.w / SUBW], 1u);
    }
    __syncthreads();
    cur[t] = atomicAdd(&tail2[t], cnt[t]);   // base within sub-bin region
    __syncthreads();
    for (int i = i0 + t; i < i1; i += 256) {
        int4 d = d4[i];
        int4 s = s4[i];
        int dd[4] = {d.x, d.y, d.z, d.w};
        int ss[4] = {s.x, s.y, s.z, s.w};
#pragma unroll
        for (int c = 0; c < 4; ++c) {
            unsigned gsb = (unsigned)dd[c] / SUBW;
            unsigned p = atomicAdd(&cur[gsb], 1u);
            if (p < (unsigned)CAP2)
                bins2[(size_t)gsb * CAP2 + p] =
                    ((unsigned)(dd[c] - gsb * SUBW) << 17) | (unsigned)ss[c];
        }
    }
}

// ---------------- K1: gemm layer 0 (fp32 A) || binall, block-range split ----------------
__global__ __launch_bounds__(256) void k_gemm0_bin(const float* __restrict__ x,
                                                   const float* __restrict__ W,
                                                   unsigned short* __restrict__ C,
                                                   const int* __restrict__ src,
                                                   const int* __restrict__ dst,
                                                   unsigned* __restrict__ bins2,
                                                   unsigned* __restrict__ tail2) {
    if (blockIdx.x < GEMM_BLOCKS)
        gemm_body<true>(x, W, nullptr, C, NN, blockIdx.x);
    else
        binall_body(src, dst, bins2, tail2, blockIdx.x - GEMM_BLOCKS);
}

__global__ __launch_bounds__(256) void k_gemm(const unsigned short* __restrict__ A,
                                              const unsigned short* __restrict__ Wsp,
                                              unsigned short* __restrict__ C) {
    gemm_body<false>(A, nullptr, Wsp, C, NN, blockIdx.x);
}

// ---------------- k_build: tail-prefix + hist + scan -> rp,dinv + scatter, fused ----------------
// Blocks 0..255: CSR build per sub-bin. Blocks 256..383: split W layers 1,2
// (k_build is 1 block/CU -- spare capacity).
__global__ __launch_bounds__(256) void k_build(const unsigned* __restrict__ bins2,
                                               const unsigned* __restrict__ tail2,
                                               int* __restrict__ rp,
                                               float* __restrict__ dinv,
                                               int* __restrict__ ssrc,
                                               float* __restrict__ pooled,
                                               const float* __restrict__ Ws,
                                               unsigned short* __restrict__ wsp) {
    int b = blockIdx.x, t = threadIdx.x;

    if (b >= NSB) {
        // W split: 2 layers x 16384 elems over 128 blocks x 256 threads
        int e = (b - NSB) * 256 + t;             // 0..32767
        int l = e >> 14;                          // 0..1 (layer-1)
        int r = e & 16383;
        int k = r >> 7;
        int c = r & 127;
        int half = c >> 6, cl = c & 63;
        float w = Ws[(size_t)(l + 1) * 16384 + k * 128 + c];
        unsigned short hb = f2bf(w);
        unsigned short lb = f2bf(w - bf2f(hb));
        size_t base = (size_t)l * WLAYER + (size_t)half * 2 * WHALF;
        wsp[base + cl * 136 + k]         = hb;
        wsp[base + WHALF + cl * 136 + k] = lb;
        return;
    }

    __shared__ int hist[SUBW];           // hist -> cursors
    __shared__ int sa[512], sd[512];
    __shared__ unsigned ta[256], tb[256];

    if (b < 65) {
        int idx = b * 256 + t;
        if (idx < GG * HH + GG) pooled[idx] = 0.f;
    }

    unsigned v = tail2[t];
    ta[t] = v;
    __syncthreads();
    unsigned *sp = ta, *dp = tb;
    for (int off = 1; off < 256; off <<= 1) {
        dp[t] = sp[t] + ((t >= off) ? sp[t - off] : 0u);
        __syncthreads();
        unsigned* tmp = sp; sp = dp; dp = tmp;
    }
    unsigned base = sp[b] - tail2[b];    // exclusive prefix for this sub-bin
    unsigned m = tail2[b];
    if (m > (unsigned)CAP2) m = CAP2;

    int lo = b * SUBW;
    int nn = NN - lo; if (nn > SUBW) nn = SUBW;
    for (int i = t; i < nn; i += 256) hist[i] = 0;
    __syncthreads();

    const unsigned* bb = bins2 + (size_t)b * CAP2;
    unsigned nv = m >> 2;
    for (unsigned i = t; i < nv; i += 256) {
        uint4 u = ((const uint4*)bb)[i];
        atomicAdd(&hist[u.x >> 17], 1);
        atomicAdd(&hist[u.y >> 17], 1);
        atomicAdd(&hist[u.z >> 17], 1);
        atomicAdd(&hist[u.w >> 17], 1);
    }
    for (unsigned i = (m & ~3u) + t; i < m; i += 256)
        atomicAdd(&hist[bb[i] >> 17], 1);
    __syncthreads();

    sa[t]       = (t < nn)       ? hist[t]       : 0;
    sa[t + 256] = (t + 256 < nn) ? hist[t + 256] : 0;
    __syncthreads();
    int* s = sa; int* d = sd;
    for (int off = 1; off < 512; off <<= 1) {
        d[t]       = s[t]       + ((t >= off)       ? s[t - off]       : 0);
        d[t + 256] = s[t + 256] + ((t + 256 >= off) ? s[t + 256 - off] : 0);
        __syncthreads();
        int* tmp = s; s = d; d = tmp;
    }

    for (int i = t; i < nn; i += 256) {
        int cur0 = (int)base + (i ? s[i - 1] : 0);
        rp[lo + i]   = cur0;
        dinv[lo + i] = rsqrtf((float)(hist[i] + 1));  // +1 self-loop
    }
    __syncthreads();
    for (int i = t; i < nn; i += 256)
        hist[i] = (int)base + (i ? s[i - 1] : 0);
    if (b == 255 && t == 0) rp[NN] = EE;
    __syncthreads();

    for (unsigned i = t; i < nv; i += 256) {
        uint4 u = ((const uint4*)bb)[i];
        int p;
        p = atomicAdd(&hist[u.x >> 17], 1); ssrc[p] = (int)(u.x & 0x1FFFFu);
        p = atomicAdd(&hist[u.y >> 17], 1); ssrc[p] = (int)(u.y & 0x1FFFFu);
        p = atomicAdd(&hist[u.z >> 17], 1); ssrc[p] = (int)(u.z & 0x1FFFFu);
        p = atomicAdd(&hist[u.w >> 17], 1); ssrc[p] = (int)(u.w & 0x1FFFFu);
    }
    for (unsigned i = (m & ~3u) + t; i < m; i += 256) {
        unsigned u = bb[i];
        int p = atomicAdd(&hist[u >> 17], 1);
        ssrc[p] = (int)(u & 0x1FFFFu);
    }
}

// ---------------- aggregate + bias + BN + ReLU ----------------
// R13 structure: 4 edges concurrently per wave. Lane (p=lane&15, gq=lane>>4)
// loads uint4 = channels [8p, 8p+8) of edge-slot gq's source row: one VMEM
// instruction gathers 4 rows (1 KB) vs round-0's 1 row (256 B). Metadata loads
// are 4-consecutive-uint2 (32 B) coalesced. Inner loop branchless: invalid
// slots clamp to end-1 (same row -> L1 hit) with dv=0. 16 edges/iter.
// Epilogue: shfl_xor(16,32) cross-group reduce; gq==0 lanes store 16 B.
// WRITE_ED (layer 0): reads ssrc + dinv gather, writes edata as byproduct.
template<bool WRITE_ED>
__global__ __launch_bounds__(256) void k_agg(const unsigned short* __restrict__ hw,
                                             const int* __restrict__ rp,
                                             const int* __restrict__ ssrc,
                                             uint2* __restrict__ edata,
                                             const float* __restrict__ dinv,
                                             const float* __restrict__ bsl,
                                             const float* __restrict__ gamma,
                                             const float* __restrict__ beta,
                                             const float* __restrict__ rm,
                                             const float* __restrict__ rv,
                                             unsigned short* __restrict__ out) {
    int lane = threadIdx.x & 63;
    int p    = lane & 15;              // channel slice [8p, 8p+8)
    int gq   = lane >> 4;              // edge slot 0..3
    int n = blockIdx.x * 4 + (threadIdx.x >> 6);
    if (n >= NN) return;
    int beg = rp[n], end = rp[n + 1];
    int c0 = p * 8;

    v2f a0 = {0.f, 0.f}, a1 = {0.f, 0.f}, a2 = {0.f, 0.f}, a3 = {0.f, 0.f};

    for (int chunk = beg; chunk < end; chunk += 16) {
#pragma unroll
        for (int jj = 0; jj < 4; ++jj) {
            int e = chunk + jj * 4 + gq;
            bool valid = (e < end);
            int ec = valid ? e : (end - 1);    // loop runs only if end > beg
            int s; float dv;
            if (WRITE_ED) {
                s  = ssrc[ec];
                float dl = dinv[s];
                dv = valid ? dl : 0.f;
                if (valid && p == 0)
                    edata[e] = make_uint2((unsigned)s, __float_as_uint(dl));
            } else {
                uint2 ed = edata[ec];
                s  = (int)ed.x;
                dv = valid ? __uint_as_float(ed.y) : 0.f;
            }
            uint4 u = *(const uint4*)(hw + (size_t)s * HH + c0);
            v2f d2 = {dv, dv};
            v2f vv;
            vv.x = __int_as_float((int)(u.x << 16));
            vv.y = __int_as_float((int)(u.x & 0xffff0000u));
            a0 += d2 * vv;
            vv.x = __int_as_float((int)(u.y << 16));
            vv.y = __int_as_float((int)(u.y & 0xffff0000u));
            a1 += d2 * vv;
            vv.x = __int_as_float((int)(u.z << 16));
            vv.y = __int_as_float((int)(u.z & 0xffff0000u));
            a2 += d2 * vv;
            vv.x = __int_as_float((int)(u.w << 16));
            vv.y = __int_as_float((int)(u.w & 0xffff0000u));
            a3 += d2 * vv;
        }
    }

    // cross-group reduce: sum over gq (lanes p, p+16, p+32, p+48)
#pragma unroll
    for (int off = 16; off < 64; off <<= 1) {
        a0.x += __shfl_xor(a0.x, off); a0.y += __shfl_xor(a0.y, off);
        a1.x += __shfl_xor(a1.x, off); a1.y += __shfl_xor(a1.y, off);
        a2.x += __shfl_xor(a2.x, off); a2.y += __shfl_xor(a2.y, off);
        a3.x += __shfl_xor(a3.x, off); a3.y += __shfl_xor(a3.y, off);
    }

    // self-loop + *dinv[n] + BN + ReLU on channels [c0, c0+8)
    float di = dinv[n];
    uint4 uh = *(const uint4*)(hw + (size_t)n * HH + c0);
    float r8[8];
    r8[0] = a0.x + di * bf2f((unsigned short)(uh.x & 0xffffu));
    r8[1] = a0.y + di * bf2f((unsigned short)(uh.x >> 16));
    r8[2] = a1.x + di * bf2f((unsigned short)(uh.y & 0xffffu));
    r8[3] = a1.y + di * bf2f((unsigned short)(uh.y >> 16));
    r8[4] = a2.x + di * bf2f((unsigned short)(uh.z & 0xffffu));
    r8[5] = a2.y + di * bf2f((unsigned short)(uh.z >> 16));
    r8[6] = a3.x + di * bf2f((unsigned short)(uh.w & 0xffffu));
    r8[7] = a3.y + di * bf2f((unsigned short)(uh.w >> 16));
    float4 gm0 = *(const float4*)(gamma + c0), gm1 = *(const float4*)(gamma + c0 + 4);
    float4 rv0 = *(const float4*)(rv + c0),    rv1 = *(const float4*)(rv + c0 + 4);
    float4 bb0 = *(const float4*)(bsl + c0),   bb1 = *(const float4*)(bsl + c0 + 4);
    float4 rm0 = *(const float4*)(rm + c0),    rm1 = *(const float4*)(rm + c0 + 4);
    float4 bt0 = *(const float4*)(beta + c0),  bt1 = *(const float4*)(beta + c0 + 4);
    float gms[8] = {gm0.x, gm0.y, gm0.z, gm0.w, gm1.x, gm1.y, gm1.z, gm1.w};
    float rvs8[8] = {rv0.x, rv0.y, rv0.z, rv0.w, rv1.x, rv1.y, rv1.z, rv1.w};
    float bbs[8] = {bb0.x, bb0.y, bb0.z, bb0.w, bb1.x, bb1.y, bb1.z, bb1.w};
    float rms8[8] = {rm0.x, rm0.y, rm0.z, rm0.w, rm1.x, rm1.y, rm1.z, rm1.w};
    float bts[8] = {bt0.x, bt0.y, bt0.z, bt0.w, bt1.x, bt1.y, bt1.z, bt1.w};
    unsigned short ob[8];
#pragma unroll
    for (int j = 0; j < 8; ++j) {
        float sc = gms[j] * rsqrtf(rvs8[j] + EPSV);
        float bj = fmaf(bbs[j] - rms8[j], sc, bts[j]);
        float y  = fmaxf(fmaf(r8[j] * di, sc, bj), 0.f);
        ob[j] = f2bf(y);
    }
    if (gq == 0) {
        uint4 o;
        o.x = (unsigned)ob[0] | ((unsigned)ob[1] << 16);
        o.y = (unsigned)ob[2] | ((unsigned)ob[3] << 16);
        o.z = (unsigned)ob[4] | ((unsigned)ob[5] << 16);
        o.w = (unsigned)ob[6] | ((unsigned)ob[7] << 16);
        *(uint4*)(out + (size_t)n * HH + c0) = o;
    }
}

// ---------------- global mean pool (batch sorted, bf16 input) ----------------
__global__ __launch_bounds__(128) void k_pool(const unsigned short* __restrict__ h,
                                              const int* __restrict__ batch,
                                              float* __restrict__ pooled,
                                              float* __restrict__ cnt) {
    int t = threadIdx.x;
    const int chunk = (NN + 2047) / 2048;  // 49
    int n0 = blockIdx.x * chunk;
    if (n0 >= NN) return;
    int n1 = n0 + chunk;
    if (n1 > NN) n1 = NN;
    int cur = batch[n0];
    float acc = 0.f;
    int k = 0;
    for (int n = n0; n < n1; ++n) {
        int b = batch[n];
        if (b != cur) {
            atomicAdd(&pooled[(size_t)cur * 128 + t], acc);
            if (t == 0) atomicAdd(&cnt[cur], (float)k);
            acc = 0.f; k = 0; cur = b;
        }
        acc += bf2f(h[(size_t)n * 128 + t]);
        ++k;
    }
    atomicAdd(&pooled[(size_t)cur * 128 + t], acc);
    if (t == 0) atomicAdd(&cnt[cur], (float)k);
}

// ---------------- LSTM (single step, h0=c0=0) + FC ----------------
__global__ __launch_bounds__(128) void k_head(const float* __restrict__ pooled,
                                              const float* __restrict__ cnt,
                                              const float* __restrict__ W_ih,
                                              const float* __restrict__ b_ih,
                                              const float* __restrict__ b_hh,
                                              const float* __restrict__ W_fc,
                                              const float* __restrict__ b_fc,
                                              float* __restrict__ out) {
    __shared__ float pm[128];
    __shared__ float gate[512];
    __shared__ float hn[128];
    int g = blockIdx.x, t = threadIdx.x;
    float cdiv = fmaxf(cnt[g], 1.0f);
    pm[t] = pooled[(size_t)g * 128 + t] / cdiv;
    __syncthreads();
    for (int j = t; j < 512; j += 128) {
        float acc = b_ih[j] + b_hh[j];
        const float* w = W_ih + (size_t)j * 128;
#pragma unroll 8
        for (int k = 0; k < 128; ++k) acc = fmaf(pm[k], w[k], acc);
        gate[j] = acc;
    }
    __syncthreads();
    {
        float gi = gate[t], gg = gate[256 + t], go = gate[384 + t];
        float cc = (1.f / (1.f + expf(-gi))) * tanhf(gg);
        hn[t] = (1.f / (1.f + expf(-go))) * tanhf(cc);
    }
    __syncthreads();
    if (t < 16) {
        float acc = b_fc[t];
        const float* w = W_fc + (size_t)t * 128;
#pragma unroll 8
        for (int k = 0; k < 128; ++k) acc = fmaf(hn[k], w[k], acc);
        out[(size_t)g * 16 + t] = acc;
    }
}

// ---------------- launch ----------------
extern "C" void kernel_launch(void* const* d_in, const int* in_sizes, int n_in,
                              void* d_out, int out_size, void* d_ws, size_t ws_size,
                              hipStream_t stream) {
    const float* x      = (const float*)d_in[0];
    const int*   ei     = (const int*)d_in[1];
    const int*   src    = ei;
    const int*   dst    = ei + EE;
    const int*   batch  = (const int*)d_in[2];
    const float* Ws     = (const float*)d_in[3];
    const float* bs     = (const float*)d_in[4];
    const float* gammas = (const float*)d_in[5];
    const float* betas  = (const float*)d_in[6];
    const float* rms    = (const float*)d_in[7];
    const float* rvs    = (const float*)d_in[8];
    const float* W_ih   = (const float*)d_in[9];
    // d_in[10] = W_hh (unused: h0 = 0)
    const float* b_ih   = (const float*)d_in[11];
    const float* b_hh   = (const float*)d_in[12];
    const float* W_fc   = (const float*)d_in[13];
    const float* b_fc   = (const float*)d_in[14];
    float* out = (float*)d_out;

    char* w = (char*)d_ws;
    unsigned*       tail2  = (unsigned*)(w + OFF_TL);
    float*          dinv   = (float*)(w + OFF_DNV);
    int*            rp     = (int*)(w + OFF_RP);
    int*            ssrc   = (int*)(w + OFF_SRC);
    unsigned*       bins2  = (unsigned*)(w + OFF_B2);
    uint2*          edata  = (uint2*)(w + OFF_ED);
    unsigned short* wsp    = (unsigned short*)(w + OFF_WS);
    unsigned short* hwb    = (unsigned short*)(w + OFF_HW);
    unsigned short* h0     = (unsigned short*)(w + OFF_H0);
    float*          pooled = (float*)(w + OFF_PL);
    float*          cntb   = pooled + (size_t)GG * HH;

    hipMemsetAsync(tail2, 0, 256 * 4, stream);

    k_gemm0_bin<<<GEMM_BLOCKS + NSB, 256, 0, stream>>>(x, Ws, hwb, src, dst, bins2, tail2);
    k_build<<<NSB + 128, 256, 0, stream>>>(bins2, tail2, rp, dinv, ssrc, pooled, Ws, wsp);

    for (int l = 0; l < 3; ++l) {
        if (l > 0)
            k_gemm<<<GEMM_BLOCKS, 256, 0, stream>>>(h0, wsp + (size_t)(l - 1) * WLAYER, hwb);
        if (l == 0)
            k_agg<true><<<(NN + 3) / 4, 256, 0, stream>>>(hwb, rp, ssrc, edata, dinv,
                                                          bs, gammas, betas, rms, rvs, h0);
        else
            k_agg<false><<<(NN + 3) / 4, 256, 0, stream>>>(hwb, rp, ssrc, edata, dinv,
                                                           bs + l * 128, gammas + l * 128,
                                                           betas + l * 128, rms + l * 128,
                                                           rvs + l * 128, h0);
    }
    k_pool<<<2048, 128, 0, stream>>>(h0, batch, pooled, cntb);
    k_head<<<GG, 128, 0, stream>>>(pooled, cntb, W_ih, b_ih, b_hh, W_fc, b_fc, out);
}

// Round 5
// 433.159 us; speedup vs baseline: 1.1582x; 1.1582x over previous
//
#include <hip/hip_runtime.h>
#include <math.h>

// ---------------- problem constants ----------------
constexpr int   NN  = 100000;    // nodes
constexpr int   EE  = 1600000;   // edges
constexpr int   HH  = 128;       // hidden / in_channels
constexpr int   GG  = 128;       // graphs
constexpr float EPSV = 1e-5f;
constexpr int   NSB = 256;                     // global sub-bins
constexpr int   SUBW = (NN + NSB - 1) / NSB;   // 391 nodes per sub-bin
constexpr int   CAP2 = 8192;                   // per-sub-bin capacity (avg 6250, +24 sigma)
constexpr int   GEMM_BLOCKS = (NN + 127) / 128;  // 782
constexpr int   WHALF = 64 * 136;                // padded ushorts per (half,hl) slab = 8704
constexpr int   WLAYER = 2 * 2 * WHALF;          // per-layer split-W ushorts (2 halves x H/L)

typedef __attribute__((ext_vector_type(8))) short  short8;
typedef __attribute__((ext_vector_type(4))) float  f32x4;
typedef __attribute__((ext_vector_type(2))) float  v2f;

__device__ __forceinline__ unsigned short f2bf(float f) {
    union { float f; unsigned u; } v; v.f = f;
    unsigned r = v.u + 0x7FFF + ((v.u >> 16) & 1);   // round-to-nearest-even
    return (unsigned short)(r >> 16);
}
__device__ __forceinline__ float bf2f(unsigned short b) {
    union { unsigned u; float f; } v; v.u = ((unsigned)b) << 16;
    return v.f;
}

// ---------------- workspace layout ----------------
constexpr size_t A256(size_t x) { return (x + 255) & ~(size_t)255; }
constexpr size_t OFF_TL  = 0;                                       // tail2[256]
constexpr size_t OFF_DNV = A256(OFF_TL  + 256 * 4);                 // N floats dinv
constexpr size_t OFF_RP  = A256(OFF_DNV + (size_t)NN * 4);          // (N+1) ints
constexpr size_t OFF_SRC = A256(OFF_RP  + (size_t)(NN + 1) * 4);    // E ints sorted src
constexpr size_t OFF_B2  = A256(OFF_SRC + (size_t)EE * 4);          // 256*CAP2 uints sub-bins
constexpr size_t OFF_ED  = A256(OFF_B2  + (size_t)NSB * CAP2 * 4);  // E uint2 (src<<8, dinv[src])
constexpr size_t OFF_WS  = A256(OFF_ED  + (size_t)EE * 8);          // 2*WLAYER ushorts split-W (layers 1,2)
constexpr size_t OFF_HW  = A256(OFF_WS  + (size_t)2 * WLAYER * 2);  // N*H bf16 (h@W)
constexpr size_t OFF_H0  = A256(OFF_HW  + (size_t)NN * HH * 2);     // N*H bf16 (h)
constexpr size_t OFF_PL  = A256(OFF_H0  + (size_t)NN * HH * 2);     // G*H f32 pooled + G f32 cnt

// ---------------- GEMM body: C[N,128] = A[N,128] @ W[128,128], MFMA bf16, split-W ----------------
template<bool FP32A>
__device__ __forceinline__ void gemm_body(const void* __restrict__ Ap,
                                          const float* __restrict__ W,
                                          const unsigned short* __restrict__ Wsp,
                                          unsigned short* __restrict__ C,
                                          int nrows, int rb) {
    __shared__ unsigned short smem[2 * WHALF];  // WtH | WtL ; reused as Cs[128][68]
    unsigned short* WtH = smem;
    unsigned short* WtL = smem + WHALF;
    int t = threadIdx.x;
    int row0 = rb * 128;
    int wv = t >> 6, lane = t & 63, m = lane & 15, q = lane >> 4;
    long rowA = row0 + wv * 32 + m;
    long rowB = rowA + 16;

    short8 a[2][4];
#pragma unroll
    for (int kc = 0; kc < 4; ++kc) {
        int ko = kc * 32 + q * 8;
        if (FP32A) {
            const float* Af = (const float*)Ap;
            float4 f0 = {0,0,0,0}, f1 = {0,0,0,0}, g0 = {0,0,0,0}, g1 = {0,0,0,0};
            if (rowA < nrows) {
                f0 = *(const float4*)(Af + rowA * 128 + ko);
                f1 = *(const float4*)(Af + rowA * 128 + ko + 4);
            }
            if (rowB < nrows) {
                g0 = *(const float4*)(Af + rowB * 128 + ko);
                g1 = *(const float4*)(Af + rowB * 128 + ko + 4);
            }
            union { short8 s; unsigned short u[8]; } ua, ub;
            ua.u[0] = f2bf(f0.x); ua.u[1] = f2bf(f0.y); ua.u[2] = f2bf(f0.z); ua.u[3] = f2bf(f0.w);
            ua.u[4] = f2bf(f1.x); ua.u[5] = f2bf(f1.y); ua.u[6] = f2bf(f1.z); ua.u[7] = f2bf(f1.w);
            ub.u[0] = f2bf(g0.x); ub.u[1] = f2bf(g0.y); ub.u[2] = f2bf(g0.z); ub.u[3] = f2bf(g0.w);
            ub.u[4] = f2bf(g1.x); ub.u[5] = f2bf(g1.y); ub.u[6] = f2bf(g1.z); ub.u[7] = f2bf(g1.w);
            a[0][kc] = ua.s; a[1][kc] = ub.s;
        } else {
            const unsigned short* Ab = (const unsigned short*)Ap;
            short8 z = {};
            a[0][kc] = (rowA < nrows) ? *(const short8*)(Ab + rowA * 128 + ko) : z;
            a[1][kc] = (rowB < nrows) ? *(const short8*)(Ab + rowB * 128 + ko) : z;
        }
    }

    for (int half = 0; half < 2; ++half) {
        int c0 = half * 64;
        __syncthreads();
        if (FP32A) {
            for (int idx = t; idx < 64 * 128; idx += 256) {
                int k = idx >> 6, c = idx & 63;
                float w = W[k * 128 + c0 + c];
                unsigned short hb = f2bf(w);
                WtH[c * 136 + k] = hb;
                WtL[c * 136 + k] = f2bf(w - bf2f(hb));
            }
        } else {
            const uint4* srcw = (const uint4*)(Wsp + (size_t)half * 2 * WHALF);
            uint4* dstw = (uint4*)smem;
            for (int i = t; i < 2176; i += 256) dstw[i] = srcw[i];
        }
        __syncthreads();
        f32x4 acc[2][4] = {};
#pragma unroll
        for (int kc = 0; kc < 4; ++kc) {
            int ko = kc * 32 + q * 8;
#pragma unroll
            for (int ct = 0; ct < 4; ++ct) {
                short8 bh = *(const short8*)(WtH + (ct * 16 + m) * 136 + ko);
                short8 bl = *(const short8*)(WtL + (ct * 16 + m) * 136 + ko);
                acc[0][ct] = __builtin_amdgcn_mfma_f32_16x16x32_bf16(a[0][kc], bh, acc[0][ct], 0, 0, 0);
                acc[0][ct] = __builtin_amdgcn_mfma_f32_16x16x32_bf16(a[0][kc], bl, acc[0][ct], 0, 0, 0);
                acc[1][ct] = __builtin_amdgcn_mfma_f32_16x16x32_bf16(a[1][kc], bh, acc[1][ct], 0, 0, 0);
                acc[1][ct] = __builtin_amdgcn_mfma_f32_16x16x32_bf16(a[1][kc], bl, acc[1][ct], 0, 0, 0);
            }
        }
        __syncthreads();
        unsigned short* Cs = smem;  // [128][68]
#pragma unroll
        for (int rt = 0; rt < 2; ++rt)
#pragma unroll
            for (int ct = 0; ct < 4; ++ct)
#pragma unroll
                for (int r = 0; r < 4; ++r) {
                    int rl = wv * 32 + rt * 16 + q * 4 + r;
                    Cs[rl * 68 + ct * 16 + m] = f2bf(acc[rt][ct][r]);
                }
        __syncthreads();
        for (int idx = t; idx < 128 * 16; idx += 256) {
            int row = idx >> 4, ch = idx & 15;
            long grow = row0 + row;
            if (grow < nrows)
                *(ushort4*)(C + grow * 128 + c0 + ch * 4) = *(const ushort4*)(Cs + row * 68 + ch * 4);
        }
    }
}

// ---------------- direct binning: edges -> 256 global sub-bins ----------------
__device__ void binall_body(const int* __restrict__ src, const int* __restrict__ dst,
                            unsigned* __restrict__ bins2, unsigned* __restrict__ tail2,
                            int b) {
    __shared__ unsigned cnt[NSB];
    __shared__ unsigned cur[NSB];
    int t = threadIdx.x;
    cnt[t] = 0;
    __syncthreads();
    const int nvec = EE / 4;                 // 400000
    int csz = (nvec + NSB - 1) / NSB;        // 1563
    int i0 = b * csz;
    int i1 = i0 + csz; if (i1 > nvec) i1 = nvec;
    const int4* d4 = (const int4*)dst;
    const int4* s4 = (const int4*)src;
    for (int i = i0 + t; i < i1; i += 256) {
        int4 d = d4[i];
        atomicAdd(&cnt[(unsigned)d.x / SUBW], 1u);
        atomicAdd(&cnt[(unsigned)d.y / SUBW], 1u);
        atomicAdd(&cnt[(unsigned)d.z / SUBW], 1u);
        atomicAdd(&cnt[(unsigned)d.w / SUBW], 1u);
    }
    __syncthreads();
    cur[t] = atomicAdd(&tail2[t], cnt[t]);   // base within sub-bin region
    __syncthreads();
    for (int i = i0 + t; i < i1; i += 256) {
        int4 d = d4[i];
        int4 s = s4[i];
        int dd[4] = {d.x, d.y, d.z, d.w};
        int ss[4] = {s.x, s.y, s.z, s.w};
#pragma unroll
        for (int c = 0; c < 4; ++c) {
            unsigned gsb = (unsigned)dd[c] / SUBW;
            unsigned p = atomicAdd(&cur[gsb], 1u);
            if (p < (unsigned)CAP2)
                bins2[(size_t)gsb * CAP2 + p] =
                    ((unsigned)(dd[c] - gsb * SUBW) << 17) | (unsigned)ss[c];
        }
    }
}

// ---------------- K1: gemm layer 0 (fp32 A) || binall, block-range split ----------------
__global__ __launch_bounds__(256) void k_gemm0_bin(const float* __restrict__ x,
                                                   const float* __restrict__ W,
                                                   unsigned short* __restrict__ C,
                                                   const int* __restrict__ src,
                                                   const int* __restrict__ dst,
                                                   unsigned* __restrict__ bins2,
                                                   unsigned* __restrict__ tail2) {
    if (blockIdx.x < GEMM_BLOCKS)
        gemm_body<true>(x, W, nullptr, C, NN, blockIdx.x);
    else
        binall_body(src, dst, bins2, tail2, blockIdx.x - GEMM_BLOCKS);
}

__global__ __launch_bounds__(256) void k_gemm(const unsigned short* __restrict__ A,
                                              const unsigned short* __restrict__ Wsp,
                                              unsigned short* __restrict__ C) {
    gemm_body<false>(A, nullptr, Wsp, C, NN, blockIdx.x);
}

// ---------------- k_build: tail-prefix + hist + scan -> rp,dinv + scatter, fused ----------------
// Blocks 0..255: CSR build per sub-bin. Blocks 256..383: split W layers 1,2
// (k_build is 1 block/CU -- spare capacity).
__global__ __launch_bounds__(256) void k_build(const unsigned* __restrict__ bins2,
                                               const unsigned* __restrict__ tail2,
                                               int* __restrict__ rp,
                                               float* __restrict__ dinv,
                                               int* __restrict__ ssrc,
                                               float* __restrict__ pooled,
                                               const float* __restrict__ Ws,
                                               unsigned short* __restrict__ wsp) {
    int b = blockIdx.x, t = threadIdx.x;

    if (b >= NSB) {
        // W split: 2 layers x 16384 elems over 128 blocks x 256 threads
        int e = (b - NSB) * 256 + t;             // 0..32767
        int l = e >> 14;                          // 0..1 (layer-1)
        int r = e & 16383;
        int k = r >> 7;
        int c = r & 127;
        int half = c >> 6, cl = c & 63;
        float w = Ws[(size_t)(l + 1) * 16384 + k * 128 + c];
        unsigned short hb = f2bf(w);
        unsigned short lb = f2bf(w - bf2f(hb));
        size_t base = (size_t)l * WLAYER + (size_t)half * 2 * WHALF;
        wsp[base + cl * 136 + k]         = hb;
        wsp[base + WHALF + cl * 136 + k] = lb;
        return;
    }

    __shared__ int hist[SUBW];           // hist -> cursors
    __shared__ int sa[512], sd[512];
    __shared__ unsigned ta[256], tb[256];

    if (b < 65) {
        int idx = b * 256 + t;
        if (idx < GG * HH + GG) pooled[idx] = 0.f;
    }

    unsigned v = tail2[t];
    ta[t] = v;
    __syncthreads();
    unsigned *sp = ta, *dp = tb;
    for (int off = 1; off < 256; off <<= 1) {
        dp[t] = sp[t] + ((t >= off) ? sp[t - off] : 0u);
        __syncthreads();
        unsigned* tmp = sp; sp = dp; dp = tmp;
    }
    unsigned base = sp[b] - tail2[b];    // exclusive prefix for this sub-bin
    unsigned m = tail2[b];
    if (m > (unsigned)CAP2) m = CAP2;

    int lo = b * SUBW;
    int nn = NN - lo; if (nn > SUBW) nn = SUBW;
    for (int i = t; i < nn; i += 256) hist[i] = 0;
    __syncthreads();

    const unsigned* bb = bins2 + (size_t)b * CAP2;
    unsigned nv = m >> 2;
    for (unsigned i = t; i < nv; i += 256) {
        uint4 u = ((const uint4*)bb)[i];
        atomicAdd(&hist[u.x >> 17], 1);
        atomicAdd(&hist[u.y >> 17], 1);
        atomicAdd(&hist[u.z >> 17], 1);
        atomicAdd(&hist[u.w >> 17], 1);
    }
    for (unsigned i = (m & ~3u) + t; i < m; i += 256)
        atomicAdd(&hist[bb[i] >> 17], 1);
    __syncthreads();

    sa[t]       = (t < nn)       ? hist[t]       : 0;
    sa[t + 256] = (t + 256 < nn) ? hist[t + 256] : 0;
    __syncthreads();
    int* s = sa; int* d = sd;
    for (int off = 1; off < 512; off <<= 1) {
        d[t]       = s[t]       + ((t >= off)       ? s[t - off]       : 0);
        d[t + 256] = s[t + 256] + ((t + 256 >= off) ? s[t + 256 - off] : 0);
        __syncthreads();
        int* tmp = s; s = d; d = tmp;
    }

    for (int i = t; i < nn; i += 256) {
        int cur0 = (int)base + (i ? s[i - 1] : 0);
        rp[lo + i]   = cur0;
        dinv[lo + i] = rsqrtf((float)(hist[i] + 1));  // +1 self-loop
    }
    __syncthreads();
    for (int i = t; i < nn; i += 256)
        hist[i] = (int)base + (i ? s[i - 1] : 0);
    if (b == 255 && t == 0) rp[NN] = EE;
    __syncthreads();

    for (unsigned i = t; i < nv; i += 256) {
        uint4 u = ((const uint4*)bb)[i];
        int p;
        p = atomicAdd(&hist[u.x >> 17], 1); ssrc[p] = (int)(u.x & 0x1FFFFu);
        p = atomicAdd(&hist[u.y >> 17], 1); ssrc[p] = (int)(u.y & 0x1FFFFu);
        p = atomicAdd(&hist[u.z >> 17], 1); ssrc[p] = (int)(u.z & 0x1FFFFu);
        p = atomicAdd(&hist[u.w >> 17], 1); ssrc[p] = (int)(u.w & 0x1FFFFu);
    }
    for (unsigned i = (m & ~3u) + t; i < m; i += 256) {
        unsigned u = bb[i];
        int p = atomicAdd(&hist[u >> 17], 1);
        ssrc[p] = (int)(u & 0x1FFFFu);
    }
}

// ---------------- aggregate + bias + BN + ReLU ----------------
// R14 structure: round-0 dependency shape (metadata once per 64-edge chunk,
// register-resident addresses, gathers issued back-to-back) but TWO edges per
// VMEM instruction: lanes 0-31 edge j (channels 4*(lane&31)..+4, 8B), lanes
// 32-63 edge j+1. One global_load_dwordx2 = 512 B (2 rows) -> 2x bytes in
// flight at same vmcnt depth, half the VMEM instructions. Per-lane address
// via __shfl(ro/dv, jb+2p+half); 8 pairs unrolled so bpermutes issue ahead of
// the load burst. edata.x holds pre-shifted row byte offset (src<<8).
// Epilogue: shfl_xor(32) cross-half reduce; lanes 0-31 store 8 B.
template<bool WRITE_ED>
__global__ __launch_bounds__(256) void k_agg(const unsigned short* __restrict__ hw,
                                             const int* __restrict__ rp,
                                             const int* __restrict__ ssrc,
                                             uint2* __restrict__ edata,
                                             const float* __restrict__ dinv,
                                             const float* __restrict__ bsl,
                                             const float* __restrict__ gamma,
                                             const float* __restrict__ beta,
                                             const float* __restrict__ rm,
                                             const float* __restrict__ rv,
                                             unsigned short* __restrict__ out) {
    int lane = threadIdx.x & 63;
    int half = lane >> 5;                  // pair slot: 0 = edge j, 1 = edge j+1
    int c4   = (lane & 31) * 4;            // 4 channels per lane
    unsigned coff = (unsigned)c4 * 2;      // byte offset within row
    int n = blockIdx.x * 4 + (threadIdx.x >> 6);
    if (n >= NN) return;
    int beg = rp[n], end = rp[n + 1];

    f32x4 accA = {0.f, 0.f, 0.f, 0.f}, accB = {0.f, 0.f, 0.f, 0.f};
    const char* hwb = (const char*)hw;

    for (int chunk = beg; chunk < end; chunk += 64) {
        int l = chunk + lane;
        unsigned ro;   // row byte offset (src<<8)
        float dv;
        if (WRITE_ED) {
            bool valid = (l < end);
            int e = valid ? ssrc[l] : n;
            float dl = dinv[e];
            dv = valid ? dl : 0.f;
            ro = (unsigned)e << 8;
            if (valid) edata[l] = make_uint2(ro, __float_as_uint(dl));
        } else {
            uint2 ed = (l < end) ? ((const uint2*)edata)[l]
                                 : make_uint2((unsigned)n << 8, 0u);
            ro = ed.x;
            dv = __uint_as_float(ed.y);
        }
        int cnt = end - chunk;
        if (cnt > 64) cnt = 64;
        for (int jb = 0; jb < cnt; jb += 16) {
#pragma unroll
            for (int p = 0; p < 8; ++p) {
                int idx = jb + 2 * p + half;
                unsigned roP = (unsigned)__shfl((int)ro, idx);
                float    dvP = __shfl(dv, idx);
                uint2 u = *(const uint2*)(hwb + (size_t)roP + coff);
                float v0 = __int_as_float((int)(u.x << 16));
                float v1 = __int_as_float((int)(u.x & 0xffff0000u));
                float v2 = __int_as_float((int)(u.y << 16));
                float v3 = __int_as_float((int)(u.y & 0xffff0000u));
                if (p & 1) {
                    accB[0] = fmaf(dvP, v0, accB[0]);
                    accB[1] = fmaf(dvP, v1, accB[1]);
                    accB[2] = fmaf(dvP, v2, accB[2]);
                    accB[3] = fmaf(dvP, v3, accB[3]);
                } else {
                    accA[0] = fmaf(dvP, v0, accA[0]);
                    accA[1] = fmaf(dvP, v1, accA[1]);
                    accA[2] = fmaf(dvP, v2, accA[2]);
                    accA[3] = fmaf(dvP, v3, accA[3]);
                }
            }
        }
    }

    float a0 = accA[0] + accB[0];
    float a1 = accA[1] + accB[1];
    float a2 = accA[2] + accB[2];
    float a3 = accA[3] + accB[3];
    // cross-half reduce (edge j sums in lanes 0-31, edge j+1 sums in 32-63)
    a0 += __shfl_xor(a0, 32);
    a1 += __shfl_xor(a1, 32);
    a2 += __shfl_xor(a2, 32);
    a3 += __shfl_xor(a3, 32);

    // self-loop + *dinv[n] + BN + ReLU on channels [c4, c4+4)
    float di = dinv[n];
    uint2 uh = *(const uint2*)(hw + (size_t)n * HH + c4);
    a0 = (a0 + di * bf2f((unsigned short)(uh.x & 0xffffu))) * di;
    a1 = (a1 + di * bf2f((unsigned short)(uh.x >> 16)))     * di;
    a2 = (a2 + di * bf2f((unsigned short)(uh.y & 0xffffu))) * di;
    a3 = (a3 + di * bf2f((unsigned short)(uh.y >> 16)))     * di;

    float4 gm  = *(const float4*)(gamma + c4);
    float4 rvv = *(const float4*)(rv + c4);
    float4 bbv = *(const float4*)(bsl + c4);
    float4 rmv = *(const float4*)(rm + c4);
    float4 btv = *(const float4*)(beta + c4);
    float s0 = gm.x * rsqrtf(rvv.x + EPSV);
    float s1 = gm.y * rsqrtf(rvv.y + EPSV);
    float s2 = gm.z * rsqrtf(rvv.z + EPSV);
    float s3 = gm.w * rsqrtf(rvv.w + EPSV);
    float y0 = fmaxf(fmaf(a0, s0, fmaf(bbv.x - rmv.x, s0, btv.x)), 0.f);
    float y1 = fmaxf(fmaf(a1, s1, fmaf(bbv.y - rmv.y, s1, btv.y)), 0.f);
    float y2 = fmaxf(fmaf(a2, s2, fmaf(bbv.z - rmv.z, s2, btv.z)), 0.f);
    float y3 = fmaxf(fmaf(a3, s3, fmaf(bbv.w - rmv.w, s3, btv.w)), 0.f);

    if (half == 0) {
        uint2 o;
        o.x = (unsigned)f2bf(y0) | ((unsigned)f2bf(y1) << 16);
        o.y = (unsigned)f2bf(y2) | ((unsigned)f2bf(y3) << 16);
        *(uint2*)(out + (size_t)n * HH + c4) = o;
    }
}

// ---------------- global mean pool (batch sorted, bf16 input) ----------------
__global__ __launch_bounds__(128) void k_pool(const unsigned short* __restrict__ h,
                                              const int* __restrict__ batch,
                                              float* __restrict__ pooled,
                                              float* __restrict__ cnt) {
    int t = threadIdx.x;
    const int chunk = (NN + 2047) / 2048;  // 49
    int n0 = blockIdx.x * chunk;
    if (n0 >= NN) return;
    int n1 = n0 + chunk;
    if (n1 > NN) n1 = NN;
    int cur = batch[n0];
    float acc = 0.f;
    int k = 0;
    for (int n = n0; n < n1; ++n) {
        int b = batch[n];
        if (b != cur) {
            atomicAdd(&pooled[(size_t)cur * 128 + t], acc);
            if (t == 0) atomicAdd(&cnt[cur], (float)k);
            acc = 0.f; k = 0; cur = b;
        }
        acc += bf2f(h[(size_t)n * 128 + t]);
        ++k;
    }
    atomicAdd(&pooled[(size_t)cur * 128 + t], acc);
    if (t == 0) atomicAdd(&cnt[cur], (float)k);
}

// ---------------- LSTM (single step, h0=c0=0) + FC ----------------
__global__ __launch_bounds__(128) void k_head(const float* __restrict__ pooled,
                                              const float* __restrict__ cnt,
                                              const float* __restrict__ W_ih,
                                              const float* __restrict__ b_ih,
                                              const float* __restrict__ b_hh,
                                              const float* __restrict__ W_fc,
                                              const float* __restrict__ b_fc,
                                              float* __restrict__ out) {
    __shared__ float pm[128];
    __shared__ float gate[512];
    __shared__ float hn[128];
    int g = blockIdx.x, t = threadIdx.x;
    float cdiv = fmaxf(cnt[g], 1.0f);
    pm[t] = pooled[(size_t)g * 128 + t] / cdiv;
    __syncthreads();
    for (int j = t; j < 512; j += 128) {
        float acc = b_ih[j] + b_hh[j];
        const float* w = W_ih + (size_t)j * 128;
#pragma unroll 8
        for (int k = 0; k < 128; ++k) acc = fmaf(pm[k], w[k], acc);
        gate[j] = acc;
    }
    __syncthreads();
    {
        float gi = gate[t], gg = gate[256 + t], go = gate[384 + t];
        float cc = (1.f / (1.f + expf(-gi))) * tanhf(gg);
        hn[t] = (1.f / (1.f + expf(-go))) * tanhf(cc);
    }
    __syncthreads();
    if (t < 16) {
        float acc = b_fc[t];
        const float* w = W_fc + (size_t)t * 128;
#pragma unroll 8
        for (int k = 0; k < 128; ++k) acc = fmaf(hn[k], w[k], acc);
        out[(size_t)g * 16 + t] = acc;
    }
}

// ---------------- launch ----------------
extern "C" void kernel_launch(void* const* d_in, const int* in_sizes, int n_in,
                              void* d_out, int out_size, void* d_ws, size_t ws_size,
                              hipStream_t stream) {
    const float* x      = (const float*)d_in[0];
    const int*   ei     = (const int*)d_in[1];
    const int*   src    = ei;
    const int*   dst    = ei + EE;
    const int*   batch  = (const int*)d_in[2];
    const float* Ws     = (const float*)d_in[3];
    const float* bs     = (const float*)d_in[4];
    const float* gammas = (const float*)d_in[5];
    const float* betas  = (const float*)d_in[6];
    const float* rms    = (const float*)d_in[7];
    const float* rvs    = (const float*)d_in[8];
    const float* W_ih   = (const float*)d_in[9];
    // d_in[10] = W_hh (unused: h0 = 0)
    const float* b_ih   = (const float*)d_in[11];
    const float* b_hh   = (const float*)d_in[12];
    const float* W_fc   = (const float*)d_in[13];
    const float* b_fc   = (const float*)d_in[14];
    float* out = (float*)d_out;

    char* w = (char*)d_ws;
    unsigned*       tail2  = (unsigned*)(w + OFF_TL);
    float*          dinv   = (float*)(w + OFF_DNV);
    int*            rp     = (int*)(w + OFF_RP);
    int*            ssrc   = (int*)(w + OFF_SRC);
    unsigned*       bins2  = (unsigned*)(w + OFF_B2);
    uint2*          edata  = (uint2*)(w + OFF_ED);
    unsigned short* wsp    = (unsigned short*)(w + OFF_WS);
    unsigned short* hwb    = (unsigned short*)(w + OFF_HW);
    unsigned short* h0     = (unsigned short*)(w + OFF_H0);
    float*          pooled = (float*)(w + OFF_PL);
    float*          cntb   = pooled + (size_t)GG * HH;

    hipMemsetAsync(tail2, 0, 256 * 4, stream);

    k_gemm0_bin<<<GEMM_BLOCKS + NSB, 256, 0, stream>>>(x, Ws, hwb, src, dst, bins2, tail2);
    k_build<<<NSB + 128, 256, 0, stream>>>(bins2, tail2, rp, dinv, ssrc, pooled, Ws, wsp);

    for (int l = 0; l < 3; ++l) {
        if (l > 0)
            k_gemm<<<GEMM_BLOCKS, 256, 0, stream>>>(h0, wsp + (size_t)(l - 1) * WLAYER, hwb);
        if (l == 0)
            k_agg<true><<<(NN + 3) / 4, 256, 0, stream>>>(hwb, rp, ssrc, edata, dinv,
                                                          bs, gammas, betas, rms, rvs, h0);
        else
            k_agg<false><<<(NN + 3) / 4, 256, 0, stream>>>(hwb, rp, ssrc, edata, dinv,
                                                           bs + l * 128, gammas + l * 128,
                                                           betas + l * 128, rms + l * 128,
                                                           rvs + l * 128, h0);
    }
    k_pool<<<2048, 128, 0, stream>>>(h0, batch, pooled, cntb);
    k_head<<<GG, 128, 0, stream>>>(pooled, cntb, W_ih, b_ih, b_hh, W_fc, b_fc, out);
}